// Round 1
// baseline (283.477 us; speedup 1.0000x reference)
//
#include <hip/hip_runtime.h>
#include <hip/hip_bf16.h>

#define Bn 256
#define Tn 512
#define Cn 256
#define Kn 8
#define LDW 264   // 256 + 8 bf16 pad: lane row-stride = 528B = 132 dwords = 4 banks

typedef __attribute__((ext_vector_type(8))) short bf16x8;
typedef __attribute__((ext_vector_type(4))) float f32x4;

__device__ __forceinline__ unsigned short f2bf(float x) {
    unsigned int u = __float_as_uint(x);
    unsigned int r = (u + 0x7FFFu + ((u >> 16) & 1u)) >> 16;  // RNE
    return (unsigned short)r;
}

__global__ void zero_out_k(float* o) { o[0] = 0.0f; }

__global__ __launch_bounds__(256, 1)
void tcon_k(const float* __restrict__ emb,
            const int* __restrict__ phon,
            const float* __restrict__ wts,
            float* __restrict__ out) {
    __shared__ unsigned short Esh[Bn * LDW];   // 135168 B bf16 normalized tile
    __shared__ int   pcls[Bn];
    __shared__ float num_s[Bn], den_s[Bn];
    __shared__ float csum[Kn];
    __shared__ int   ccnt[Kn];

    const int t    = blockIdx.x;
    const int tid  = threadIdx.x;
    const int lane = tid & 63;
    const int wave = tid >> 6;

    if (tid < Kn) { csum[tid] = 0.0f; ccnt[tid] = 0; }
    pcls[tid] = phon[tid * Tn + t];   // phonemes[i, t]

    // ---- Phase 1: load fp32 rows, L2-normalize, store bf16 to LDS ----
    #pragma unroll 4
    for (int i = wave; i < Bn; i += 4) {
        const float4 v = ((const float4*)(emb + ((size_t)i * Tn + t) * Cn))[lane];
        float ss = v.x * v.x + v.y * v.y + v.z * v.z + v.w * v.w;
        #pragma unroll
        for (int m = 32; m >= 1; m >>= 1) ss += __shfl_xor(ss, m, 64);
        const float inv = 1.0f / fmaxf(sqrtf(ss), 1e-12f);
        ushort4 pk;
        pk.x = f2bf(v.x * inv); pk.y = f2bf(v.y * inv);
        pk.z = f2bf(v.z * inv); pk.w = f2bf(v.w * inv);
        *(ushort4*)&Esh[i * LDW + 4 * lane] = pk;
    }
    __syncthreads();

    // ---- Phase 2: S = E E^T via MFMA, fused exp + masked row sums ----
    const int q   = lane >> 4;    // quad 0..3
    const int l15 = lane & 15;
    const int i0  = wave * 64;    // this wave's 64 output rows

    float num_p[16], den_p[16];
    int   pi[16], irow[16];
    #pragma unroll
    for (int e = 0; e < 16; ++e) {
        num_p[e] = 0.0f; den_p[e] = 0.0f;
        irow[e]  = i0 + (e >> 2) * 16 + q * 4 + (e & 3);  // C/D: row = quad*4 + reg
        pi[e]    = pcls[irow[e]];
    }

    #pragma unroll
    for (int s = 0; s < 4; ++s) {          // 64-wide j-strips
        const int jb = s * 64;
        f32x4 acc[4][4];
        #pragma unroll
        for (int a = 0; a < 4; ++a)
            #pragma unroll
            for (int b = 0; b < 4; ++b)
                acc[a][b] = (f32x4){0.f, 0.f, 0.f, 0.f};

        #pragma unroll
        for (int kk = 0; kk < 8; ++kk) {   // K loop, 8 x 32
            const int kb = kk * 32 + q * 8;
            bf16x8 afr[4], bfr[4];
            #pragma unroll
            for (int mi = 0; mi < 4; ++mi)
                afr[mi] = *(const bf16x8*)&Esh[(i0 + mi * 16 + l15) * LDW + kb];
            #pragma unroll
            for (int nj = 0; nj < 4; ++nj)
                bfr[nj] = *(const bf16x8*)&Esh[(jb + nj * 16 + l15) * LDW + kb];
            #pragma unroll
            for (int mi = 0; mi < 4; ++mi)
                #pragma unroll
                for (int nj = 0; nj < 4; ++nj)
                    acc[mi][nj] = __builtin_amdgcn_mfma_f32_16x16x32_bf16(
                        afr[mi], bfr[nj], acc[mi][nj], 0, 0, 0);
        }

        // fused epilogue for this strip
        #pragma unroll
        for (int nj = 0; nj < 4; ++nj) {
            const int j  = jb + nj * 16 + l15;   // C/D: col = lane&15
            const int pj = pcls[j];
            #pragma unroll
            for (int mi = 0; mi < 4; ++mi) {
                #pragma unroll
                for (int r = 0; r < 4; ++r) {
                    const int e = mi * 4 + r;
                    const float ex = __expf(acc[mi][nj][r]);
                    const bool nd = (irow[e] != j);
                    den_p[e] += nd ? ex : 0.0f;
                    num_p[e] += (nd && (pj == pi[e])) ? ex : 0.0f;
                }
            }
        }
    }

    // reduce partials across the 16 lanes of each quad (lane bits 0..3)
    #pragma unroll
    for (int e = 0; e < 16; ++e) {
        float n = num_p[e], d = den_p[e];
        #pragma unroll
        for (int m = 1; m <= 8; m <<= 1) {
            n += __shfl_xor(n, m, 64);
            d += __shfl_xor(d, m, 64);
        }
        if (l15 == e) { num_s[irow[e]] = n; den_s[irow[e]] = d; }
    }
    __syncthreads();

    // ---- Phase 3: per-sample loss, per-class means, weighted mean ----
    {
        const float ps = __logf(den_s[tid] + 1e-6f) - __logf(num_s[tid]);
        atomicAdd(&csum[pcls[tid]], ps);
        atomicAdd(&ccnt[pcls[tid]], 1);
    }
    __syncthreads();

    if (tid == 0) {
        float accv = 0.0f; int np = 0;
        #pragma unroll
        for (int k = 0; k < Kn; ++k) {
            if (ccnt[k] > 0) {
                accv += (csum[k] / (float)ccnt[k]) * wts[k];
                ++np;
            }
        }
        atomicAdd(out, (accv / (float)np) * (1.0f / (float)Tn));
    }
}

extern "C" void kernel_launch(void* const* d_in, const int* in_sizes, int n_in,
                              void* d_out, int out_size, void* d_ws, size_t ws_size,
                              hipStream_t stream) {
    const float* emb  = (const float*)d_in[0];
    const int*   phon = (const int*)d_in[1];
    const float* wts  = (const float*)d_in[2];
    float*       out  = (float*)d_out;

    zero_out_k<<<1, 1, 0, stream>>>(out);
    tcon_k<<<Tn, 256, 0, stream>>>(emb, phon, wts, out);
}

// Round 2
// 237.249 us; speedup vs baseline: 1.1948x; 1.1948x over previous
//
#include <hip/hip_runtime.h>

#define Bn 256
#define Tn 512
#define Cn 256
#define Kn 8

typedef __attribute__((ext_vector_type(8))) short bf16x8;
typedef __attribute__((ext_vector_type(4))) float f32x4;

__device__ __forceinline__ unsigned short f2bf(float x) {
    unsigned int u = __float_as_uint(x);
    return (unsigned short)((u + 0x7FFFu + ((u >> 16) & 1u)) >> 16);  // RNE
}

__global__ void zero_out_k(float* o) { o[0] = 0.0f; }

// 512 threads = 8 waves (2/SIMD). Wave w: rows i0=(w>>1)*64, cols jb0=(w&1)*128.
// LDS tile is XOR-swizzled: 16B-block c at (row,c) stored at c ^ (row&7).
__global__ __launch_bounds__(512, 2)
void tcon_k(const float* __restrict__ emb,
            const int* __restrict__ phon,
            const float* __restrict__ wts,
            float* __restrict__ out) {
    __shared__ unsigned short Esh[Bn * Cn];    // 131072 B, bf16, swizzled
    __shared__ float invn[Bn];
    __shared__ int   pcls[Bn];
    __shared__ float num_s[Bn], den_s[Bn];
    __shared__ float csum[Kn];
    __shared__ int   ccnt[Kn];

    const int t    = blockIdx.x;
    const int tid  = threadIdx.x;
    const int lane = tid & 63;
    const int wave = tid >> 6;

    if (tid < Kn) { csum[tid] = 0.0f; ccnt[tid] = 0; }
    if (tid < Bn) {
        pcls[tid]  = phon[tid * Tn + t];
        num_s[tid] = 0.0f;
        den_s[tid] = 0.0f;
    }

    // ---- Phase 1: stream fp32 -> bf16 into swizzled LDS (no reductions) ----
    #pragma unroll 4
    for (int f = tid; f < Bn * 64; f += 512) {
        const int row = f >> 6;
        const int c2  = f & 63;                 // float4 index within row
        const float4 v = *((const float4*)(emb + ((size_t)row * Tn + t) * Cn) + c2);
        ushort4 pk;
        pk.x = f2bf(v.x); pk.y = f2bf(v.y); pk.z = f2bf(v.z); pk.w = f2bf(v.w);
        const int c    = c2 >> 1;               // 16B block index 0..31
        const int half = c2 & 1;
        *(ushort4*)&Esh[row * Cn + (((c ^ (row & 7)) << 3) + (half << 2))] = pk;
    }
    __syncthreads();

    // ---- Phase 2: S = E E^T (raw, unnormalized) via MFMA ----
    const int q   = lane >> 4;
    const int l15 = lane & 15;
    const int i0  = (wave >> 1) * 64;
    const int jb0 = (wave & 1) * 128;

    f32x4 acc[2][4][4];   // [strip][mi][nj]
    #pragma unroll
    for (int s = 0; s < 2; ++s)
        #pragma unroll
        for (int a = 0; a < 4; ++a)
            #pragma unroll
            for (int b = 0; b < 4; ++b)
                acc[s][a][b] = (f32x4){0.f, 0.f, 0.f, 0.f};

    #pragma unroll
    for (int kk = 0; kk < 8; ++kk) {
        const int cq = kk * 4 + q;             // 16B block index along K
        bf16x8 afr[4], bfr[2][4];
        #pragma unroll
        for (int mi = 0; mi < 4; ++mi) {
            const int row = i0 + mi * 16 + l15;
            afr[mi] = *(const bf16x8*)&Esh[row * Cn + ((cq ^ (row & 7)) << 3)];
        }
        #pragma unroll
        for (int s = 0; s < 2; ++s)
            #pragma unroll
            for (int nj = 0; nj < 4; ++nj) {
                const int row = jb0 + s * 64 + nj * 16 + l15;
                bfr[s][nj] = *(const bf16x8*)&Esh[row * Cn + ((cq ^ (row & 7)) << 3)];
            }
        #pragma unroll
        for (int s = 0; s < 2; ++s)
            #pragma unroll
            for (int mi = 0; mi < 4; ++mi)
                #pragma unroll
                for (int nj = 0; nj < 4; ++nj)
                    acc[s][mi][nj] = __builtin_amdgcn_mfma_f32_16x16x32_bf16(
                        afr[mi], bfr[s][nj], acc[s][mi][nj], 0, 0, 0);
    }

    // ---- Diagonal -> inverse norms (waves whose col-range contains their rows) ----
    if ((wave >> 2) == (wave & 1)) {
        const int sd = (wave >> 1) & 1;        // local strip containing the diagonal
        if (q == (l15 >> 2)) {                 // lanes holding diag elements (l15 == q*4+r)
            #pragma unroll
            for (int mi = 0; mi < 4; ++mi) {
                const int rowg = i0 + mi * 16 + l15;
                invn[rowg] = rsqrtf(fmaxf(acc[sd][mi][mi][l15 & 3], 1e-24f));
            }
        }
    }
    __syncthreads();

    // ---- Epilogue: normalize, exp, masked row sums ----
    float num_p[16], den_p[16], inv_i[16];
    int   pi[16];
    #pragma unroll
    for (int e = 0; e < 16; ++e) {
        const int irow = i0 + (e >> 2) * 16 + q * 4 + (e & 3);
        num_p[e] = 0.0f; den_p[e] = 0.0f;
        pi[e]    = pcls[irow];
        inv_i[e] = invn[irow];
    }

    #pragma unroll
    for (int s = 0; s < 2; ++s)
        #pragma unroll
        for (int nj = 0; nj < 4; ++nj) {
            const int j    = jb0 + s * 64 + nj * 16 + l15;
            const int pj   = pcls[j];
            const float ij = invn[j];
            #pragma unroll
            for (int mi = 0; mi < 4; ++mi)
                #pragma unroll
                for (int r = 0; r < 4; ++r) {
                    const int e = mi * 4 + r;
                    const int irow = i0 + mi * 16 + q * 4 + r;
                    const float ex = __expf(acc[s][mi][nj][r] * inv_i[e] * ij);
                    const bool nd = (irow != j);
                    den_p[e] += nd ? ex : 0.0f;
                    num_p[e] += (nd && (pj == pi[e])) ? ex : 0.0f;
                }
        }

    // reduce over the 16 lanes of each quad-row group, accumulate across wave pair
    #pragma unroll
    for (int e = 0; e < 16; ++e) {
        float n = num_p[e], d = den_p[e];
        #pragma unroll
        for (int m = 1; m <= 8; m <<= 1) {
            n += __shfl_xor(n, m, 64);
            d += __shfl_xor(d, m, 64);
        }
        if (l15 == e) {
            const int irow = i0 + (e >> 2) * 16 + q * 4 + (e & 3);
            atomicAdd(&num_s[irow], n);
            atomicAdd(&den_s[irow], d);
        }
    }
    __syncthreads();

    // ---- Phase 3: per-sample loss, class means, weighted mean ----
    if (tid < Bn) {
        const float ps = __logf(den_s[tid] + 1e-6f) - __logf(num_s[tid]);
        atomicAdd(&csum[pcls[tid]], ps);
        atomicAdd(&ccnt[pcls[tid]], 1);
    }
    __syncthreads();

    if (tid == 0) {
        float accv = 0.0f; int np = 0;
        #pragma unroll
        for (int k = 0; k < Kn; ++k)
            if (ccnt[k] > 0) { accv += (csum[k] / (float)ccnt[k]) * wts[k]; ++np; }
        atomicAdd(out, (accv / (float)np) * (1.0f / (float)Tn));
    }
}

extern "C" void kernel_launch(void* const* d_in, const int* in_sizes, int n_in,
                              void* d_out, int out_size, void* d_ws, size_t ws_size,
                              hipStream_t stream) {
    const float* emb  = (const float*)d_in[0];
    const int*   phon = (const int*)d_in[1];
    const float* wts  = (const float*)d_in[2];
    float*       out  = (float*)d_out;

    zero_out_k<<<1, 1, 0, stream>>>(out);
    tcon_k<<<Tn, 512, 0, stream>>>(emb, phon, wts, out);
}

// Round 3
// 218.385 us; speedup vs baseline: 1.2981x; 1.0864x over previous
//
#include <hip/hip_runtime.h>

#define Bn 256
#define Tn 512
#define Cn 256
#define Kn 8

typedef __attribute__((ext_vector_type(8))) short bf16x8;
typedef __attribute__((ext_vector_type(4))) float f32x4;

__device__ __forceinline__ unsigned short f2bf(float x) {
    unsigned int u = __float_as_uint(x);
    return (unsigned short)((u + 0x7FFFu + ((u >> 16) & 1u)) >> 16);  // RNE
}

__global__ void zero_out_k(float* o) { o[0] = 0.0f; }

// 512 threads = 8 waves (2/SIMD). Wave w: rows i0=(w>>1)*64, cols jb0=(w&1)*128.
// LDS tile is XOR-swizzled: 16B-block c at (row,c) stored at c ^ (row&7).
__global__ __launch_bounds__(512, 2)
void tcon_k(const float* __restrict__ emb,
            const int* __restrict__ phon,
            const float* __restrict__ wts,
            float* __restrict__ out) {
    __shared__ unsigned short Esh[Bn * Cn];    // 131072 B, bf16, swizzled
    __shared__ float invn[Bn];
    __shared__ int   pcls[Bn];
    __shared__ float num_s[Bn], den_s[Bn];
    __shared__ float csum[Kn];
    __shared__ int   ccnt[Kn];

    const int t    = blockIdx.x;
    const int tid  = threadIdx.x;
    const int lane = tid & 63;
    const int wave = tid >> 6;

    if (tid < Kn) { csum[tid] = 0.0f; ccnt[tid] = 0; }
    if (tid < Bn) {
        pcls[tid]  = phon[tid * Tn + t];
        num_s[tid] = 0.0f;
        den_s[tid] = 0.0f;
    }

    // ---- Phase 1: stream fp32 -> bf16 into swizzled LDS (no reductions) ----
    #pragma unroll 8
    for (int f = tid; f < Bn * 64; f += 512) {
        const int row = f >> 6;
        const int c2  = f & 63;                 // float4 index within row
        const float4 v = *((const float4*)(emb + ((size_t)row * Tn + t) * Cn) + c2);
        ushort4 pk;
        pk.x = f2bf(v.x); pk.y = f2bf(v.y); pk.z = f2bf(v.z); pk.w = f2bf(v.w);
        const int c    = c2 >> 1;               // 16B block index 0..31
        const int half = c2 & 1;
        *(ushort4*)&Esh[row * Cn + (((c ^ (row & 7)) << 3) + (half << 2))] = pk;
    }
    __syncthreads();

    // ---- Phase 2: S = E E^T (raw, unnormalized) via MFMA ----
    const int q   = lane >> 4;
    const int l15 = lane & 15;
    const int i0  = (wave >> 1) * 64;
    const int jb0 = (wave & 1) * 128;

    f32x4 acc[2][4][4];   // [strip][mi][nj] — ALL indices compile-time constant
    #pragma unroll
    for (int s = 0; s < 2; ++s)
        #pragma unroll
        for (int a = 0; a < 4; ++a)
            #pragma unroll
            for (int b = 0; b < 4; ++b)
                acc[s][a][b] = (f32x4){0.f, 0.f, 0.f, 0.f};

    #pragma unroll
    for (int kk = 0; kk < 8; ++kk) {
        const int cq = kk * 4 + q;             // 16B block index along K
        bf16x8 afr[4], bfr[2][4];
        #pragma unroll
        for (int mi = 0; mi < 4; ++mi) {
            const int row = i0 + mi * 16 + l15;
            afr[mi] = *(const bf16x8*)&Esh[row * Cn + ((cq ^ (row & 7)) << 3)];
        }
        #pragma unroll
        for (int s = 0; s < 2; ++s)
            #pragma unroll
            for (int nj = 0; nj < 4; ++nj) {
                const int row = jb0 + s * 64 + nj * 16 + l15;
                bfr[s][nj] = *(const bf16x8*)&Esh[row * Cn + ((cq ^ (row & 7)) << 3)];
            }
        #pragma unroll
        for (int s = 0; s < 2; ++s)
            #pragma unroll
            for (int mi = 0; mi < 4; ++mi)
                #pragma unroll
                for (int nj = 0; nj < 4; ++nj)
                    acc[s][mi][nj] = __builtin_amdgcn_mfma_f32_16x16x32_bf16(
                        afr[mi], bfr[s][nj], acc[s][mi][nj], 0, 0, 0);
    }

    // ---- Diagonal -> inverse norms. Constant indices only (no scratch spill!).
    // Waves whose col range contains their row range: w=0 (strip0), w=2 (strip1),
    // w=5 (strip0), w=7 (strip1). Diag element: acc[strip][mi][mi][r] at lanes
    // l15 == q*4+r.
    if ((wave >> 2) == (wave & 1)) {
        if (((wave >> 1) & 1) == 0) {
            #pragma unroll
            for (int r = 0; r < 4; ++r)
                if (l15 == q * 4 + r) {
                    #pragma unroll
                    for (int mi = 0; mi < 4; ++mi)
                        invn[i0 + mi * 16 + l15] =
                            rsqrtf(fmaxf(acc[0][mi][mi][r], 1e-24f));
                }
        } else {
            #pragma unroll
            for (int r = 0; r < 4; ++r)
                if (l15 == q * 4 + r) {
                    #pragma unroll
                    for (int mi = 0; mi < 4; ++mi)
                        invn[i0 + mi * 16 + l15] =
                            rsqrtf(fmaxf(acc[1][mi][mi][r], 1e-24f));
                }
        }
    }
    __syncthreads();

    // ---- Epilogue: normalize, exp, masked row sums ----
    float num_p[16], den_p[16], inv_i[16];
    int   pi[16];
    #pragma unroll
    for (int e = 0; e < 16; ++e) {
        const int irow = i0 + (e >> 2) * 16 + q * 4 + (e & 3);
        num_p[e] = 0.0f; den_p[e] = 0.0f;
        pi[e]    = pcls[irow];
        inv_i[e] = invn[irow];
    }

    #pragma unroll
    for (int s = 0; s < 2; ++s)
        #pragma unroll
        for (int nj = 0; nj < 4; ++nj) {
            const int j    = jb0 + s * 64 + nj * 16 + l15;
            const int pj   = pcls[j];
            const float ij = invn[j];
            #pragma unroll
            for (int mi = 0; mi < 4; ++mi)
                #pragma unroll
                for (int r = 0; r < 4; ++r) {
                    const int e = mi * 4 + r;
                    const int irow = i0 + mi * 16 + q * 4 + r;
                    const float ex = __expf(acc[s][mi][nj][r] * inv_i[e] * ij);
                    const bool nd = (irow != j);
                    den_p[e] += nd ? ex : 0.0f;
                    num_p[e] += (nd && (pj == pi[e])) ? ex : 0.0f;
                }
        }

    // reduce over the 16 lanes of each quad-row group, accumulate across wave pair
    #pragma unroll
    for (int e = 0; e < 16; ++e) {
        float n = num_p[e], d = den_p[e];
        #pragma unroll
        for (int m = 1; m <= 8; m <<= 1) {
            n += __shfl_xor(n, m, 64);
            d += __shfl_xor(d, m, 64);
        }
        if (l15 == e) {
            const int irow = i0 + (e >> 2) * 16 + q * 4 + (e & 3);
            atomicAdd(&num_s[irow], n);
            atomicAdd(&den_s[irow], d);
        }
    }
    __syncthreads();

    // ---- Phase 3: per-sample loss, class means, weighted mean ----
    if (tid < Bn) {
        const float ps = __logf(den_s[tid] + 1e-6f) - __logf(num_s[tid]);
        atomicAdd(&csum[pcls[tid]], ps);
        atomicAdd(&ccnt[pcls[tid]], 1);
    }
    __syncthreads();

    if (tid == 0) {
        float accv = 0.0f; int np = 0;
        #pragma unroll
        for (int k = 0; k < Kn; ++k)
            if (ccnt[k] > 0) { accv += (csum[k] / (float)ccnt[k]) * wts[k]; ++np; }
        atomicAdd(out, (accv / (float)np) * (1.0f / (float)Tn));
    }
}

extern "C" void kernel_launch(void* const* d_in, const int* in_sizes, int n_in,
                              void* d_out, int out_size, void* d_ws, size_t ws_size,
                              hipStream_t stream) {
    const float* emb  = (const float*)d_in[0];
    const int*   phon = (const int*)d_in[1];
    const float* wts  = (const float*)d_in[2];
    float*       out  = (float*)d_out;

    zero_out_k<<<1, 1, 0, stream>>>(out);
    tcon_k<<<Tn, 512, 0, stream>>>(emb, phon, wts, out);
}

// Round 4
// 208.221 us; speedup vs baseline: 1.3614x; 1.0488x over previous
//
#include <hip/hip_runtime.h>

#define Bn 256
#define Tn 512
#define Cn 256
#define Kn 8

typedef __attribute__((ext_vector_type(4))) float f32x4;

// 512 threads = 8 waves (4/SIMD with 2 blocks/CU). Wave w owns output rows
// [w*32, w*32+32) and iterates all four 64-wide j-strips sequentially.
// LDS tile: fp8 e4m3, paired-K layout: logical 8-byte half-unit b=kk*4+q
// (k-bytes [kk*32+q*8, +8)) stored at physical unit u=(q*4+kp)^(row&7) (16B),
// half (kk&1) — so one ds_read_b128 feeds MFMAs for kk=2kp and 2kp+1.
__global__ __launch_bounds__(512, 4)
void tcon_k(const float* __restrict__ emb,
            const int* __restrict__ phon,
            const float* __restrict__ wts,
            float* __restrict__ out) {
    __shared__ __align__(16) unsigned char Esh[Bn * Bn];   // 64 KiB fp8
    __shared__ float invn[Bn];
    __shared__ int   pcls[Bn];
    __shared__ float num_s[Bn], den_s[Bn];
    __shared__ float csum[Kn];
    __shared__ int   ccnt[Kn];

    const int t    = blockIdx.x;
    const int tid  = threadIdx.x;
    const int lane = tid & 63;
    const int wave = tid >> 6;

    if (tid < Kn) { csum[tid] = 0.0f; ccnt[tid] = 0; }
    if (tid < Bn) pcls[tid] = phon[tid * Tn + t];

    // ---- Phase 1: stream fp32 -> fp8 e4m3 into paired-K swizzled LDS ----
    #pragma unroll 4
    for (int it = 0; it < 16; ++it) {
        const int f   = tid + it * 512;
        const int row = f >> 5;
        const int b   = f & 31;                 // logical 8B half-unit
        const float4* p = (const float4*)(emb + ((size_t)row * Tn + t) * Cn);
        const float4 v0 = p[2 * b];
        const float4 v1 = p[2 * b + 1];
        int lo = __builtin_amdgcn_cvt_pk_fp8_f32(v0.x, v0.y, 0, false);
        lo     = __builtin_amdgcn_cvt_pk_fp8_f32(v0.z, v0.w, lo, true);
        int hi = __builtin_amdgcn_cvt_pk_fp8_f32(v1.x, v1.y, 0, false);
        hi     = __builtin_amdgcn_cvt_pk_fp8_f32(v1.z, v1.w, hi, true);
        const int q  = b & 3;
        const int kk = b >> 2;
        const int kp = kk >> 1;
        const int addr = row * 256 + ((((q << 2) + kp) ^ (row & 7)) << 4)
                       + ((kk & 1) << 3);
        int2 pk; pk.x = lo; pk.y = hi;
        *(int2*)&Esh[addr] = pk;
    }
    __syncthreads();

    // ---- Phase 2: S = E E^T via fp8 MFMA, strip-sequential ----
    const int q   = lane >> 4;
    const int l15 = lane & 15;
    const int e3  = l15 & 7;       // == row&7 for all our fragment rows
    const int i0  = wave * 32;
    const int sd  = wave >> 1;     // strip containing this wave's diagonal

    f32x4 acc[2][4];

#define ZERO_ACC() do {                                                      \
    _Pragma("unroll") for (int _m = 0; _m < 2; ++_m)                         \
    _Pragma("unroll") for (int _n = 0; _n < 4; ++_n)                         \
        acc[_m][_n] = (f32x4){0.f, 0.f, 0.f, 0.f};                           \
} while (0)

#define COMPUTE_STRIP(JB) do {                                               \
    ZERO_ACC();                                                              \
    _Pragma("unroll") for (int kp = 0; kp < 4; ++kp) {                       \
        const int sw = (((q << 2) + kp) ^ e3) << 4;                          \
        ulonglong2 _a[2], _b[4];                                             \
        _Pragma("unroll") for (int _m = 0; _m < 2; ++_m)                     \
            _a[_m] = *(const ulonglong2*)&Esh[(i0 + _m * 16 + l15) * 256 + sw]; \
        _Pragma("unroll") for (int _n = 0; _n < 4; ++_n)                     \
            _b[_n] = *(const ulonglong2*)&Esh[((JB) + _n * 16 + l15) * 256 + sw]; \
        _Pragma("unroll") for (int _m = 0; _m < 2; ++_m)                     \
        _Pragma("unroll") for (int _n = 0; _n < 4; ++_n) {                   \
            acc[_m][_n] = __builtin_amdgcn_mfma_f32_16x16x32_fp8_fp8(        \
                (long)_a[_m].x, (long)_b[_n].x, acc[_m][_n], 0, 0, 0);       \
            acc[_m][_n] = __builtin_amdgcn_mfma_f32_16x16x32_fp8_fp8(        \
                (long)_a[_m].y, (long)_b[_n].y, acc[_m][_n], 0, 0, 0);       \
        }                                                                    \
    }                                                                        \
} while (0)

#define EPILOGUE(JB) do {                                                    \
    _Pragma("unroll") for (int _n = 0; _n < 4; ++_n) {                       \
        const int _j  = (JB) + _n * 16 + l15;                                \
        const int _pj = pcls[_j];                                            \
        const float _ij = invn[_j];                                          \
        _Pragma("unroll") for (int _m = 0; _m < 2; ++_m)                     \
        _Pragma("unroll") for (int _r = 0; _r < 4; ++_r) {                   \
            const int _e = _m * 4 + _r;                                      \
            const int _ir = i0 + _m * 16 + q * 4 + _r;                       \
            const float _ex = __expf(acc[_m][_n][_r] * inv_i[_e] * _ij);     \
            const bool _nd = (_ir != _j);                                    \
            den_p[_e] += _nd ? _ex : 0.0f;                                   \
            num_p[_e] += (_nd && (_pj == pi[_e])) ? _ex : 0.0f;              \
        }                                                                    \
    }                                                                        \
} while (0)

    // Strip sd first -> diagonal -> norms (constant register indices only)
    COMPUTE_STRIP(sd * 64);
    if ((wave & 1) == 0) {          // rows at strip offset 0..31 -> nj = mi
        #pragma unroll
        for (int r = 0; r < 4; ++r)
            if (l15 == q * 4 + r) {
                invn[i0 + l15]      = rsqrtf(fmaxf(acc[0][0][r], 1e-24f));
                invn[i0 + 16 + l15] = rsqrtf(fmaxf(acc[1][1][r], 1e-24f));
            }
    } else {                        // rows at strip offset 32..63 -> nj = 2+mi
        #pragma unroll
        for (int r = 0; r < 4; ++r)
            if (l15 == q * 4 + r) {
                invn[i0 + l15]      = rsqrtf(fmaxf(acc[0][2][r], 1e-24f));
                invn[i0 + 16 + l15] = rsqrtf(fmaxf(acc[1][3][r], 1e-24f));
            }
    }
    __syncthreads();               // all norms published

    float num_p[8], den_p[8], inv_i[8];
    int   pi[8];
    #pragma unroll
    for (int e = 0; e < 8; ++e) {
        const int irow = i0 + (e >> 2) * 16 + q * 4 + (e & 3);
        num_p[e] = 0.0f; den_p[e] = 0.0f;
        pi[e]    = pcls[irow];
        inv_i[e] = invn[irow];
    }

    EPILOGUE(sd * 64);             // consume held diagonal-strip acc
    for (int s = 0; s < 4; ++s) {  // remaining strips (wave-uniform skip)
        if (s == sd) continue;
        COMPUTE_STRIP(s * 64);
        EPILOGUE(s * 64);
    }

    // Reduce across the 16 l15 lanes of each quad; each row owned by 1 wave.
    #pragma unroll
    for (int e = 0; e < 8; ++e) {
        float n = num_p[e], d = den_p[e];
        #pragma unroll
        for (int m = 1; m <= 8; m <<= 1) {
            n += __shfl_xor(n, m, 64);
            d += __shfl_xor(d, m, 64);
        }
        if (l15 == e) {
            const int irow = i0 + (e >> 2) * 16 + q * 4 + (e & 3);
            num_s[irow] = n;
            den_s[irow] = d;
        }
    }
    __syncthreads();

    // ---- Phase 3: per-sample loss, class means, weighted mean ----
    if (tid < Bn) {
        const float ps = __logf(den_s[tid] + 1e-6f) - __logf(num_s[tid]);
        atomicAdd(&csum[pcls[tid]], ps);
        atomicAdd(&ccnt[pcls[tid]], 1);
    }
    __syncthreads();

    if (tid == 0) {
        float accv = 0.0f; int np = 0;
        #pragma unroll
        for (int k = 0; k < Kn; ++k)
            if (ccnt[k] > 0) { accv += (csum[k] / (float)ccnt[k]) * wts[k]; ++np; }
        atomicAdd(out, (accv / (float)np) * (1.0f / (float)Tn));
    }
#undef ZERO_ACC
#undef COMPUTE_STRIP
#undef EPILOGUE
}

extern "C" void kernel_launch(void* const* d_in, const int* in_sizes, int n_in,
                              void* d_out, int out_size, void* d_ws, size_t ws_size,
                              hipStream_t stream) {
    const float* emb  = (const float*)d_in[0];
    const int*   phon = (const int*)d_in[1];
    const float* wts  = (const float*)d_in[2];
    float*       out  = (float*)d_out;

    hipMemsetAsync(out, 0, sizeof(float), stream);
    tcon_k<<<Tn, 512, 0, stream>>>(emb, phon, wts, out);
}